// Round 9
// baseline (97.597 us; speedup 1.0000x reference)
//
#include <hip/hip_runtime.h>
#include <stdint.h>

#define NB 4
#define SS 192
#define NI 256

typedef __attribute__((ext_vector_type(8))) short bf16x8;
typedef __attribute__((ext_vector_type(16))) float f32x16;

__device__ __forceinline__ uint16_t f2bf(float f) {
  union { float f; uint32_t u; } v; v.f = f;
  return (uint16_t)((v.u + 0x7FFFu + ((v.u >> 16) & 1u)) >> 16);
}

__device__ __forceinline__ uint32_t bfmul2(uint32_t x, uint32_t y) {
  union { float f; uint32_t u; } xa, xb, ya, yb, r0, r1;
  xa.u = x << 16;        ya.u = y << 16;
  xb.u = x & 0xFFFF0000u; yb.u = y & 0xFFFF0000u;
  r0.f = xa.f * ya.f;
  r1.f = xb.f * yb.f;
  uint32_t lo = (r0.u + 0x7FFFu + ((r0.u >> 16) & 1u)) >> 16;
  uint32_t hi = (r1.u + 0x7FFFu + ((r1.u >> 16) & 1u)) >> 16;
  return lo | (hi << 16);
}

// ---------------- K_PS: proj->scores, 144 blocks x 1024 threads ----------------
// 4 independent PS units per block (unit = tid>>8, R8-validated body).
// LDS padded to 96 KB -> hardware allows only 1 block/CU -> guaranteed spread
// across 144 distinct CUs regardless of dispatch policy.
__global__ __launch_bounds__(1024) void k_ps(
    const float* __restrict__ h_head, const float* __restrict__ h_dep,
    const float* __restrict__ h_sib,
    const float* __restrict__ U, const float* __restrict__ V,
    const float* __restrict__ Z,
    float* __restrict__ s_hd, float* __restrict__ s_hs,
    float* __restrict__ s_ds) {
  __shared__ float ahf[4][4 * NI];     // 16 KB
  __shared__ float rbuf[4][5 * 1024];  // 80 KB (last 1 KB/unit = occupancy pad)
  const int tid = threadIdx.x;
  const int un = tid >> 8, t = tid & 255;
  const int gu = blockIdx.x * 4 + un;           // 0..575
  const int which = gu / 192, rem = gu % 192;
  const int b = rem / 48, x0 = (rem % 48) * 4;
  const float* A  = (which == 2) ? h_dep : h_head;
  const float* M  = (which == 0) ? U : (which == 1) ? V : Z;
  const float* Bm = (which == 0) ? h_dep : h_sib;
  float* outp = (which == 0) ? s_hd : (which == 1) ? s_hs : s_ds;

  #pragma unroll
  for (int r = 0; r < 4; ++r) ahf[un][r * NI + t] = A[(b * SS + x0 + r) * NI + t];
  __syncthreads();

  // M-phase: thread (cq, ig) accumulates rows 0..3 x cols 4cq..4cq+3 over ig-quarter of i
  const int cq = t & 63, ig = t >> 6;
  const float* Mp = M + (size_t)(ig * 64) * NI + 4 * cq;
  const float* w0p = ahf[un] + 0 * NI + ig * 64;
  const float* w1p = ahf[un] + 1 * NI + ig * 64;
  const float* w2p = ahf[un] + 2 * NI + ig * 64;
  const float* w3p = ahf[un] + 3 * NI + ig * 64;
  float4 a0 = {0,0,0,0}, a1 = a0, a2 = a0, a3 = a0;
  #pragma unroll 8
  for (int ii = 0; ii < 64; ++ii) {
    const float4 m = *(const float4*)(Mp + (size_t)ii * NI);
    const float w0 = w0p[ii], w1 = w1p[ii], w2 = w2p[ii], w3 = w3p[ii];
    a0.x += m.x * w0; a0.y += m.y * w0; a0.z += m.z * w0; a0.w += m.w * w0;
    a1.x += m.x * w1; a1.y += m.y * w1; a1.z += m.z * w1; a1.w += m.w * w1;
    a2.x += m.x * w2; a2.y += m.y * w2; a2.z += m.z * w2; a2.w += m.w * w2;
    a3.x += m.x * w3; a3.y += m.y * w3; a3.z += m.z * w3; a3.w += m.w * w3;
  }
  {
    float* rb = rbuf[un] + ig * 1024 + 4 * cq;
    *(float4*)(rb + 0 * NI) = a0;
    *(float4*)(rb + 1 * NI) = a1;
    *(float4*)(rb + 2 * NI) = a2;
    *(float4*)(rb + 3 * NI) = a3;
  }
  __syncthreads();
  #pragma unroll
  for (int r = 0; r < 4; ++r)
    ahf[un][r * NI + t] = rbuf[un][r * NI + t] + rbuf[un][1024 + r * NI + t]
                        + rbuf[un][2048 + r * NI + t] + rbuf[un][3072 + r * NI + t];
  __syncthreads();

  // score phase: y = t, dot 4 projected rows against Bm[y]
  if (t < SS) {
    const float4* brow = (const float4*)(Bm + (b * SS + t) * NI);
    float acc[4] = {};
    for (int c = 0; c < NI / 4; ++c) {
      const float4 bv = brow[c];
      #pragma unroll
      for (int r = 0; r < 4; ++r) {
        const float4 av = ((const float4*)(ahf[un] + r * NI))[c];
        acc[r] += av.x * bv.x + av.y * bv.y + av.z * bv.z + av.w * bv.w;
      }
    }
    #pragma unroll
    for (int r = 0; r < 4; ++r) outp[(b * SS + x0 + r) * SS + t] = acc[r];
  }
}

// ---------------- K_W: W_tri partials + HH/HS bf16 converts (2048 blocks) ----------------
__global__ void k_w(const float* __restrict__ W,
                    const float* __restrict__ h_head, const float* __restrict__ h_sib,
                    float* __restrict__ partial,
                    uint16_t* __restrict__ HH, uint16_t* __restrict__ HS) {
  __shared__ float red[4];
  const int c = blockIdx.x, tid = threadIdx.x;
  const float4* pw = (const float4*)(W + (size_t)c * 8192);
  float4 a = {0.f, 0.f, 0.f, 0.f};
  #pragma unroll
  for (int it = 0; it < 8; ++it) {
    const float4 v = pw[it * 256 + tid];
    a.x += v.x; a.y += v.y; a.z += v.z; a.w += v.w;
  }
  float s = (a.x + a.y) + (a.z + a.w);
  for (int off = 32; off > 0; off >>= 1) s += __shfl_down(s, off, 64);
  if ((tid & 63) == 0) red[tid >> 6] = s;
  __syncthreads();
  if (tid == 0) partial[c] = red[0] + red[1] + red[2] + red[3];
  if (c < NB * SS) {
    const int g = c * NI + tid;
    HH[g] = f2bf(h_head[g]);
    HS[g] = f2bf(h_sib[g]);
  }
}

// ---------------- K3: 32x32x16 MFMA GEMM (validated R8 body) ----------------
__global__ __launch_bounds__(384, 3) void k3_big(
    const uint16_t* __restrict__ HH, const uint16_t* __restrict__ HS,
    const float* __restrict__ h_dep, const float* __restrict__ partial,
    const float* __restrict__ s_hd, const float* __restrict__ s_hs,
    const float* __restrict__ s_ds,
    const float* __restrict__ bias, float* __restrict__ out) {
  __shared__ __align__(16) uint16_t Btile[SS * 128];   // 48 KB (HS, swizzled)
  __shared__ __align__(16) uint16_t Atile[96 * 128];   // 24 KB (HH*cvec, swizzled)
  __shared__ uint16_t cvec[NI];
  const int d = blockIdx.x, hb = blockIdx.y, b = blockIdx.z;
  const int tid = threadIdx.x;
  const int lane = tid & 63, w = tid >> 6;
  const int whb = (w >> 1) * 32;
  const int wsb = (w & 1) * 96;
  const int l31 = lane & 31, l5 = lane >> 5;
  const int kc = tid & 15;

  if (tid < NI) {
    float wr = 0.f;
    #pragma unroll
    for (int q = 0; q < 8; ++q) wr += partial[8 * tid + q];
    cvec[tid] = f2bf(wr * h_dep[(b * SS + d) * NI + tid]);
  }
  __syncthreads();

  f32x16 acc0 = {}, acc1 = {}, acc2 = {};

  #pragma unroll
  for (int half = 0; half < 2; ++half) {
    const int kbase = half * 128;
    #pragma unroll
    for (int i = 0; i < 8; ++i) {
      const int slot = (w * 8 + i) * 64 + lane;
      const int row = slot >> 4;
      const int kcs = (slot & 15) ^ (row & 15);
      const uint16_t* src = HS + ((b * SS + row) << 8) + kbase + kcs * 8;
      __builtin_amdgcn_global_load_lds(
          (const __attribute__((address_space(1))) void*)src,
          (__attribute__((address_space(3))) void*)(Btile + (size_t)(w * 8 + i) * 512),
          16, 0, 0);
    }
    const uint4 cv4 = *(const uint4*)(cvec + kbase + kc * 8);
    #pragma unroll
    for (int i = 0; i < 4; ++i) {
      const int c = i * 384 + tid;
      const int row = c >> 4;
      const uint4 hh4 = *(const uint4*)(HH + ((b * SS + hb * 96 + row) << 8) + kbase + kc * 8);
      uint4 a4;
      a4.x = bfmul2(hh4.x, cv4.x);
      a4.y = bfmul2(hh4.y, cv4.y);
      a4.z = bfmul2(hh4.z, cv4.z);
      a4.w = bfmul2(hh4.w, cv4.w);
      *(uint4*)((char*)Atile + row * 256 + ((kc ^ (row & 15)) << 4)) = a4;
    }
    __syncthreads();
    const int arow = whb + l31;
    const int abyte = arow * 256;
    const int amask = (arow & 15);
    #pragma unroll
    for (int ks = 0; ks < 8; ++ks) {
      const int sl = ks * 2 + l5;
      bf16x8 af = *reinterpret_cast<const bf16x8*>((const char*)Atile + abyte + ((sl ^ amask) << 4));
      {
        const int brow = wsb + l31;
        bf16x8 bf = *reinterpret_cast<const bf16x8*>((const char*)Btile + brow * 256 + ((sl ^ (brow & 15)) << 4));
        acc0 = __builtin_amdgcn_mfma_f32_32x32x16_bf16(af, bf, acc0, 0, 0, 0);
      }
      {
        const int brow = wsb + 32 + l31;
        bf16x8 bf = *reinterpret_cast<const bf16x8*>((const char*)Btile + brow * 256 + ((sl ^ (brow & 15)) << 4));
        acc1 = __builtin_amdgcn_mfma_f32_32x32x16_bf16(af, bf, acc1, 0, 0, 0);
      }
      {
        const int brow = wsb + 64 + l31;
        bf16x8 bf = *reinterpret_cast<const bf16x8*>((const char*)Btile + brow * 256 + ((sl ^ (brow & 15)) << 4));
        acc2 = __builtin_amdgcn_mfma_f32_32x32x16_bf16(af, bf, acc2, 0, 0, 0);
      }
    }
    __syncthreads();
  }

  const float bias0 = bias[0];
  float chd[16];
  #pragma unroll
  for (int r = 0; r < 16; ++r) {
    const int h = hb * 96 + whb + (r & 3) + 8 * (r >> 2) + 4 * l5;
    chd[r] = s_hd[(b * SS + h) * SS + d] + bias0;
  }
  #pragma unroll
  for (int t = 0; t < 3; ++t) {
    const int s = wsb + t * 32 + l31;
    const float dsv = s_ds[(b * SS + d) * SS + s];
    const f32x16 a = (t == 0) ? acc0 : (t == 1) ? acc1 : acc2;
    #pragma unroll
    for (int r = 0; r < 16; ++r) {
      const int h = hb * 96 + whb + (r & 3) + 8 * (r >> 2) + 4 * l5;
      const float v = a[r] + chd[r] + s_hs[(b * SS + h) * SS + s] + dsv;
      out[((size_t)(b * SS + h) * SS + d) * SS + s] = v;
    }
  }
}

extern "C" void kernel_launch(void* const* d_in, const int* in_sizes, int n_in,
                              void* d_out, int out_size, void* d_ws, size_t ws_size,
                              hipStream_t stream) {
  const float* h_head = (const float*)d_in[0];
  const float* h_dep  = (const float*)d_in[1];
  const float* h_sib  = (const float*)d_in[2];
  const float* W_tri  = (const float*)d_in[3];
  const float* U_hd   = (const float*)d_in[4];
  const float* V_hs   = (const float*)d_in[5];
  const float* Z_ds   = (const float*)d_in[6];
  const float* bias   = (const float*)d_in[7];
  float* out = (float*)d_out;

  float* ws = (float*)d_ws;
  float* partial = ws;          ws += 2048;
  float* s_hd    = ws;          ws += NB * SS * SS;
  float* s_hs    = ws;          ws += NB * SS * SS;
  float* s_ds    = ws;          ws += NB * SS * SS;
  uint16_t* HH   = (uint16_t*)ws;
  uint16_t* HS   = HH + 768 * NI;

  k_ps<<<144, 1024, 0, stream>>>(h_head, h_dep, h_sib, U_hd, V_hs, Z_ds,
                                 s_hd, s_hs, s_ds);
  k_w<<<2048, 256, 0, stream>>>(W_tri, h_head, h_sib, partial, HH, HS);
  k3_big<<<dim3(SS, 2, NB), 384, 0, stream>>>(HH, HS, h_dep, partial,
                                              s_hd, s_hs, s_ds, bias, out);
}

// Round 10
// 85.344 us; speedup vs baseline: 1.1436x; 1.1436x over previous
//
#include <hip/hip_runtime.h>
#include <stdint.h>

#define NB 4
#define SS 192
#define NI 256

typedef __attribute__((ext_vector_type(8))) short bf16x8;
typedef __attribute__((ext_vector_type(16))) float f32x16;

__device__ __forceinline__ uint16_t f2bf(float f) {
  union { float f; uint32_t u; } v; v.f = f;
  return (uint16_t)((v.u + 0x7FFFu + ((v.u >> 16) & 1u)) >> 16);
}

__device__ __forceinline__ uint32_t bfmul2(uint32_t x, uint32_t y) {
  union { float f; uint32_t u; } xa, xb, ya, yb, r0, r1;
  xa.u = x << 16;        ya.u = y << 16;
  xb.u = x & 0xFFFF0000u; yb.u = y & 0xFFFF0000u;
  r0.f = xa.f * ya.f;
  r1.f = xb.f * yb.f;
  uint32_t lo = (r0.u + 0x7FFFu + ((r0.u >> 16) & 1u)) >> 16;
  uint32_t hi = (r1.u + 0x7FFFu + ((r1.u >> 16) & 1u)) >> 16;
  return lo | (hi << 16);
}

// ---------------- K1: proj->scores (blocks 0..575) + W_tri partials (576..2623) ----------------
// R8 structure verbatim; __launch_bounds__(256) added so the compiler budgets
// VGPRs for a 256-thread block (default assumes 1024 threads -> ~64 VGPR cap,
// which strangles the unroll-8 M-phase load pipeline).
__global__ __launch_bounds__(256) void k1_fused(
                         const float* __restrict__ W,
                         const float* __restrict__ h_head, const float* __restrict__ h_dep,
                         const float* __restrict__ h_sib,
                         const float* __restrict__ U, const float* __restrict__ V,
                         const float* __restrict__ Z,
                         float* __restrict__ partial,
                         uint16_t* __restrict__ HH, uint16_t* __restrict__ HS,
                         float* __restrict__ s_hd, float* __restrict__ s_hs,
                         float* __restrict__ s_ds) {
  __shared__ float ahf[4 * NI];          // A rows, later reused as reduced projection tf
  __shared__ float rbuf[4 * 4 * NI];     // per-i-group partial projections
  __shared__ float red[4];
  const int bi = blockIdx.x, tid = threadIdx.x;

  if (bi >= 576) {
    // ---- W-chunk block: sum 8192 consecutive floats of W_tri ----
    const int c = bi - 576;              // 0..2047
    const float4* pw = (const float4*)(W + (size_t)c * 8192);
    float4 a = {0.f, 0.f, 0.f, 0.f};
    #pragma unroll
    for (int it = 0; it < 8; ++it) {
      const float4 v = pw[it * 256 + tid];
      a.x += v.x; a.y += v.y; a.z += v.z; a.w += v.w;
    }
    float s = (a.x + a.y) + (a.z + a.w);
    for (int off = 32; off > 0; off >>= 1) s += __shfl_down(s, off, 64);
    if ((tid & 63) == 0) red[tid >> 6] = s;
    __syncthreads();
    if (tid == 0) partial[c] = red[0] + red[1] + red[2] + red[3];
    if (c < NB * SS) {
      const int g = c * NI + tid;
      HH[g] = f2bf(h_head[g]);
      HS[g] = f2bf(h_sib[g]);
    }
    return;
  }

  // ---- proj->score block ----
  const int u = bi;
  const int which = u / 192, rem = u % 192;
  const int b = rem / 48, x0 = (rem % 48) * 4;
  const float* A  = (which == 2) ? h_dep : h_head;
  const float* M  = (which == 0) ? U : (which == 1) ? V : Z;
  const float* Bm = (which == 0) ? h_dep : h_sib;
  float* outp = (which == 0) ? s_hd : (which == 1) ? s_hs : s_ds;

  #pragma unroll
  for (int r = 0; r < 4; ++r) ahf[r * NI + tid] = A[(b * SS + x0 + r) * NI + tid];
  __syncthreads();

  // M-phase: thread (cq, ig) accumulates rows 0..3 x cols 4cq..4cq+3 over i in ig-quarter
  const int cq = tid & 63, ig = tid >> 6;
  const float* Mp = M + (size_t)(ig * 64) * NI + 4 * cq;
  const float* w0p = ahf + 0 * NI + ig * 64;
  const float* w1p = ahf + 1 * NI + ig * 64;
  const float* w2p = ahf + 2 * NI + ig * 64;
  const float* w3p = ahf + 3 * NI + ig * 64;
  float4 a0 = {0,0,0,0}, a1 = a0, a2 = a0, a3 = a0;
  #pragma unroll 8
  for (int ii = 0; ii < 64; ++ii) {
    const float4 m = *(const float4*)(Mp + (size_t)ii * NI);
    const float w0 = w0p[ii], w1 = w1p[ii], w2 = w2p[ii], w3 = w3p[ii];
    a0.x += m.x * w0; a0.y += m.y * w0; a0.z += m.z * w0; a0.w += m.w * w0;
    a1.x += m.x * w1; a1.y += m.y * w1; a1.z += m.z * w1; a1.w += m.w * w1;
    a2.x += m.x * w2; a2.y += m.y * w2; a2.z += m.z * w2; a2.w += m.w * w2;
    a3.x += m.x * w3; a3.y += m.y * w3; a3.z += m.z * w3; a3.w += m.w * w3;
  }
  {
    float* rb = rbuf + ig * 1024 + 4 * cq;
    *(float4*)(rb + 0 * NI) = a0;
    *(float4*)(rb + 1 * NI) = a1;
    *(float4*)(rb + 2 * NI) = a2;
    *(float4*)(rb + 3 * NI) = a3;
  }
  __syncthreads();
  #pragma unroll
  for (int r = 0; r < 4; ++r)
    ahf[r * NI + tid] = rbuf[r * NI + tid] + rbuf[1024 + r * NI + tid]
                      + rbuf[2048 + r * NI + tid] + rbuf[3072 + r * NI + tid];
  __syncthreads();

  // score phase (validated): y = tid, dot 4 projected rows against Bm[y]
  if (tid < SS) {
    const float4* brow = (const float4*)(Bm + (b * SS + tid) * NI);
    float acc[4] = {};
    for (int c = 0; c < NI / 4; ++c) {
      const float4 bv = brow[c];
      #pragma unroll
      for (int r = 0; r < 4; ++r) {
        const float4 av = ((const float4*)(ahf + r * NI))[c];
        acc[r] += av.x * bv.x + av.y * bv.y + av.z * bv.z + av.w * bv.w;
      }
    }
    #pragma unroll
    for (int r = 0; r < 4; ++r) outp[(b * SS + x0 + r) * SS + tid] = acc[r];
  }
}

// ---------------- K3: 32x32x16 MFMA GEMM (validated R8 body) ----------------
__global__ __launch_bounds__(384, 3) void k3_big(
    const uint16_t* __restrict__ HH, const uint16_t* __restrict__ HS,
    const float* __restrict__ h_dep, const float* __restrict__ partial,
    const float* __restrict__ s_hd, const float* __restrict__ s_hs,
    const float* __restrict__ s_ds,
    const float* __restrict__ bias, float* __restrict__ out) {
  __shared__ __align__(16) uint16_t Btile[SS * 128];   // 48 KB (HS, swizzled)
  __shared__ __align__(16) uint16_t Atile[96 * 128];   // 24 KB (HH*cvec, swizzled)
  __shared__ uint16_t cvec[NI];
  const int d = blockIdx.x, hb = blockIdx.y, b = blockIdx.z;
  const int tid = threadIdx.x;
  const int lane = tid & 63, w = tid >> 6;
  const int whb = (w >> 1) * 32;
  const int wsb = (w & 1) * 96;
  const int l31 = lane & 31, l5 = lane >> 5;
  const int kc = tid & 15;

  if (tid < NI) {
    float wr = 0.f;
    #pragma unroll
    for (int q = 0; q < 8; ++q) wr += partial[8 * tid + q];
    cvec[tid] = f2bf(wr * h_dep[(b * SS + d) * NI + tid]);
  }
  __syncthreads();

  f32x16 acc0 = {}, acc1 = {}, acc2 = {};

  #pragma unroll
  for (int half = 0; half < 2; ++half) {
    const int kbase = half * 128;
    #pragma unroll
    for (int i = 0; i < 8; ++i) {
      const int slot = (w * 8 + i) * 64 + lane;
      const int row = slot >> 4;
      const int kcs = (slot & 15) ^ (row & 15);
      const uint16_t* src = HS + ((b * SS + row) << 8) + kbase + kcs * 8;
      __builtin_amdgcn_global_load_lds(
          (const __attribute__((address_space(1))) void*)src,
          (__attribute__((address_space(3))) void*)(Btile + (size_t)(w * 8 + i) * 512),
          16, 0, 0);
    }
    const uint4 cv4 = *(const uint4*)(cvec + kbase + kc * 8);
    #pragma unroll
    for (int i = 0; i < 4; ++i) {
      const int c = i * 384 + tid;
      const int row = c >> 4;
      const uint4 hh4 = *(const uint4*)(HH + ((b * SS + hb * 96 + row) << 8) + kbase + kc * 8);
      uint4 a4;
      a4.x = bfmul2(hh4.x, cv4.x);
      a4.y = bfmul2(hh4.y, cv4.y);
      a4.z = bfmul2(hh4.z, cv4.z);
      a4.w = bfmul2(hh4.w, cv4.w);
      *(uint4*)((char*)Atile + row * 256 + ((kc ^ (row & 15)) << 4)) = a4;
    }
    __syncthreads();
    const int arow = whb + l31;
    const int abyte = arow * 256;
    const int amask = (arow & 15);
    #pragma unroll
    for (int ks = 0; ks < 8; ++ks) {
      const int sl = ks * 2 + l5;
      bf16x8 af = *reinterpret_cast<const bf16x8*>((const char*)Atile + abyte + ((sl ^ amask) << 4));
      {
        const int brow = wsb + l31;
        bf16x8 bf = *reinterpret_cast<const bf16x8*>((const char*)Btile + brow * 256 + ((sl ^ (brow & 15)) << 4));
        acc0 = __builtin_amdgcn_mfma_f32_32x32x16_bf16(af, bf, acc0, 0, 0, 0);
      }
      {
        const int brow = wsb + 32 + l31;
        bf16x8 bf = *reinterpret_cast<const bf16x8*>((const char*)Btile + brow * 256 + ((sl ^ (brow & 15)) << 4));
        acc1 = __builtin_amdgcn_mfma_f32_32x32x16_bf16(af, bf, acc1, 0, 0, 0);
      }
      {
        const int brow = wsb + 64 + l31;
        bf16x8 bf = *reinterpret_cast<const bf16x8*>((const char*)Btile + brow * 256 + ((sl ^ (brow & 15)) << 4));
        acc2 = __builtin_amdgcn_mfma_f32_32x32x16_bf16(af, bf, acc2, 0, 0, 0);
      }
    }
    __syncthreads();
  }

  const float bias0 = bias[0];
  float chd[16];
  #pragma unroll
  for (int r = 0; r < 16; ++r) {
    const int h = hb * 96 + whb + (r & 3) + 8 * (r >> 2) + 4 * l5;
    chd[r] = s_hd[(b * SS + h) * SS + d] + bias0;
  }
  #pragma unroll
  for (int t = 0; t < 3; ++t) {
    const int s = wsb + t * 32 + l31;
    const float dsv = s_ds[(b * SS + d) * SS + s];
    const f32x16 a = (t == 0) ? acc0 : (t == 1) ? acc1 : acc2;
    #pragma unroll
    for (int r = 0; r < 16; ++r) {
      const int h = hb * 96 + whb + (r & 3) + 8 * (r >> 2) + 4 * l5;
      const float v = a[r] + chd[r] + s_hs[(b * SS + h) * SS + s] + dsv;
      out[((size_t)(b * SS + h) * SS + d) * SS + s] = v;
    }
  }
}

extern "C" void kernel_launch(void* const* d_in, const int* in_sizes, int n_in,
                              void* d_out, int out_size, void* d_ws, size_t ws_size,
                              hipStream_t stream) {
  const float* h_head = (const float*)d_in[0];
  const float* h_dep  = (const float*)d_in[1];
  const float* h_sib  = (const float*)d_in[2];
  const float* W_tri  = (const float*)d_in[3];
  const float* U_hd   = (const float*)d_in[4];
  const float* V_hs   = (const float*)d_in[5];
  const float* Z_ds   = (const float*)d_in[6];
  const float* bias   = (const float*)d_in[7];
  float* out = (float*)d_out;

  float* ws = (float*)d_ws;
  float* partial = ws;          ws += 2048;
  float* s_hd    = ws;          ws += NB * SS * SS;
  float* s_hs    = ws;          ws += NB * SS * SS;
  float* s_ds    = ws;          ws += NB * SS * SS;
  uint16_t* HH   = (uint16_t*)ws;
  uint16_t* HS   = HH + 768 * NI;

  k1_fused<<<2624, 256, 0, stream>>>(W_tri, h_head, h_dep, h_sib, U_hd, V_hs, Z_ds,
                                     partial, HH, HS, s_hd, s_hs, s_ds);
  k3_big<<<dim3(SS, 2, NB), 384, 0, stream>>>(HH, HS, h_dep, partial,
                                              s_hd, s_hs, s_ds, bias, out);
}

// Round 11
// 78.326 us; speedup vs baseline: 1.2460x; 1.0896x over previous
//
#include <hip/hip_runtime.h>
#include <stdint.h>

#define NB 4
#define SS 192
#define NI 256

typedef __attribute__((ext_vector_type(8))) short bf16x8;
typedef __attribute__((ext_vector_type(16))) float f32x16;

__device__ __forceinline__ uint16_t f2bf(float f) {
  union { float f; uint32_t u; } v; v.f = f;
  return (uint16_t)((v.u + 0x7FFFu + ((v.u >> 16) & 1u)) >> 16);
}

__device__ __forceinline__ uint4 pack8(const float4 a, const float4 b) {
  uint4 r;
  r.x = (uint32_t)f2bf(a.x) | ((uint32_t)f2bf(a.y) << 16);
  r.y = (uint32_t)f2bf(a.z) | ((uint32_t)f2bf(a.w) << 16);
  r.z = (uint32_t)f2bf(b.x) | ((uint32_t)f2bf(b.y) << 16);
  r.w = (uint32_t)f2bf(b.z) | ((uint32_t)f2bf(b.w) << 16);
  return r;
}

__device__ __forceinline__ uint32_t bfmul2(uint32_t x, uint32_t y) {
  union { float f; uint32_t u; } xa, xb, ya, yb, r0, r1;
  xa.u = x << 16;        ya.u = y << 16;
  xb.u = x & 0xFFFF0000u; yb.u = y & 0xFFFF0000u;
  r0.f = xa.f * ya.f;
  r1.f = xb.f * yb.f;
  uint32_t lo = (r0.u + 0x7FFFu + ((r0.u >> 16) & 1u)) >> 16;
  uint32_t hi = (r1.u + 0x7FFFu + ((r1.u >> 16) & 1u)) >> 16;
  return lo | (hi << 16);
}

// Canonical bf16 storage: row-major, 8-elem chunks permuted c8 -> c8 ^ (row&15).

// ---------------- K0: W_tri partials (0..2047) + bf16 converts (2048..2175) ----------------
__global__ __launch_bounds__(256) void k0(
    const float* __restrict__ W,
    const float* __restrict__ h_head, const float* __restrict__ h_dep, const float* __restrict__ h_sib,
    const float* __restrict__ U, const float* __restrict__ V, const float* __restrict__ Z,
    float* __restrict__ partial,
    uint16_t* __restrict__ HH, uint16_t* __restrict__ HD, uint16_t* __restrict__ HS,
    uint16_t* __restrict__ U16, uint16_t* __restrict__ V16, uint16_t* __restrict__ Z16) {
  __shared__ float red[4];
  const int bi = blockIdx.x, tid = threadIdx.x;
  if (bi < 2048) {
    const float4* pw = (const float4*)(W + (size_t)bi * 8192);
    float4 a = {0.f, 0.f, 0.f, 0.f};
    #pragma unroll
    for (int it = 0; it < 8; ++it) {
      const float4 v = pw[it * 256 + tid];
      a.x += v.x; a.y += v.y; a.z += v.z; a.w += v.w;
    }
    float s = (a.x + a.y) + (a.z + a.w);
    for (int off = 32; off > 0; off >>= 1) s += __shfl_down(s, off, 64);
    if ((tid & 63) == 0) red[tid >> 6] = s;
    __syncthreads();
    if (tid == 0) partial[bi] = red[0] + red[1] + red[2] + red[3];
    return;
  }
  const int rl = tid >> 5, c8 = tid & 31;
  if (bi < 2144) {
    const int g = (bi - 2048) * 8 + rl;            // 0..767
    const int dst = g * 32 + (c8 ^ (g & 15));
    const int srci = g * 64 + c8 * 2;
    { const float4 x = ((const float4*)h_head)[srci], y = ((const float4*)h_head)[srci + 1];
      ((uint4*)HH)[dst] = pack8(x, y); }
    { const float4 x = ((const float4*)h_dep)[srci], y = ((const float4*)h_dep)[srci + 1];
      ((uint4*)HD)[dst] = pack8(x, y); }
    { const float4 x = ((const float4*)h_sib)[srci], y = ((const float4*)h_sib)[srci + 1];
      ((uint4*)HS)[dst] = pack8(x, y); }
  } else {
    const int g = (bi - 2144) * 8 + rl;            // 0..255
    const int dst = g * 32 + (c8 ^ (g & 15));
    const int srci = g * 64 + c8 * 2;
    { const float4 x = ((const float4*)U)[srci], y = ((const float4*)U)[srci + 1];
      ((uint4*)U16)[dst] = pack8(x, y); }
    { const float4 x = ((const float4*)V)[srci], y = ((const float4*)V)[srci + 1];
      ((uint4*)V16)[dst] = pack8(x, y); }
    { const float4 x = ((const float4*)Z)[srci], y = ((const float4*)Z)[srci + 1];
      ((uint4*)Z16)[dst] = pack8(x, y); }
  }
}

// ---------------- K1 stage-1: dU/T2/TZ = A(192xK) x B(U/V/Z rows)^T, MFMA ----------------
// grid (3, 2, 4) = (which, n-tile of 128, b). 256 threads = 4 waves (1 n-strip each).
__global__ __launch_bounds__(256, 2) void k_s1(
    const uint16_t* __restrict__ HD, const uint16_t* __restrict__ HS,
    const uint16_t* __restrict__ U16, const uint16_t* __restrict__ V16, const uint16_t* __restrict__ Z16,
    uint16_t* __restrict__ dU16, uint16_t* __restrict__ T216, uint16_t* __restrict__ TZ16) {
  __shared__ __align__(16) uint16_t Ah[192 * 128];   // 48 KB
  __shared__ __align__(16) uint16_t Bh[128 * 128];   // 32 KB
  const int which = blockIdx.x, nt = blockIdx.y, b = blockIdx.z;
  const uint16_t* As = (which == 0) ? HD : HS;
  const uint16_t* Bs = (which == 0) ? U16 : (which == 1) ? V16 : Z16;
  uint16_t* Os = (which == 0) ? dU16 : (which == 1) ? T216 : TZ16;
  const int tid = threadIdx.x, lane = tid & 63, w = tid >> 6;
  const int l31 = lane & 31, l5 = lane >> 5;
  const int N0 = nt * 128;
  f32x16 acc[6] = {};

  #pragma unroll
  for (int kh = 0; kh < 2; ++kh) {
    const int kbase = kh * 128;
    if (kh) __syncthreads();
    #pragma unroll
    for (int i = 0; i < 12; ++i) {
      const int slot = i * 256 + tid;
      const int row = slot >> 4, ck = slot & 15;
      const uint16_t* src = As + (size_t)(b * SS + row) * NI + kbase + ck * 8;
      __builtin_amdgcn_global_load_lds((const __attribute__((address_space(1))) void*)src,
          (__attribute__((address_space(3))) void*)(Ah + (size_t)slot * 8), 16, 0, 0);
    }
    #pragma unroll
    for (int i = 0; i < 8; ++i) {
      const int slot = i * 256 + tid;
      const int row = slot >> 4, ck = slot & 15;
      const uint16_t* src = Bs + (size_t)(N0 + row) * NI + kbase + ck * 8;
      __builtin_amdgcn_global_load_lds((const __attribute__((address_space(1))) void*)src,
          (__attribute__((address_space(3))) void*)(Bh + (size_t)slot * 8), 16, 0, 0);
    }
    __syncthreads();
    const int brow = w * 32 + l31;
    const int bbyte = brow * 256;
    const int bmask = brow & 15;
    #pragma unroll
    for (int ks = 0; ks < 8; ++ks) {
      const int sl = ks * 2 + l5;
      bf16x8 bf = *reinterpret_cast<const bf16x8*>((const char*)Bh + bbyte + ((sl ^ bmask) << 4));
      #pragma unroll
      for (int mt = 0; mt < 6; ++mt) {
        const int ar = mt * 32 + l31;
        bf16x8 af = *reinterpret_cast<const bf16x8*>((const char*)Ah + ar * 256 + ((sl ^ (ar & 15)) << 4));
        acc[mt] = __builtin_amdgcn_mfma_f32_32x32x16_bf16(af, bf, acc[mt], 0, 0, 0);
      }
    }
  }
  const int n = N0 + w * 32 + l31;
  const int nck = n >> 3, npos = n & 7;
  #pragma unroll
  for (int mt = 0; mt < 6; ++mt) {
    #pragma unroll
    for (int r = 0; r < 16; ++r) {
      const int m = mt * 32 + (r & 3) + 8 * (r >> 2) + 4 * l5;
      Os[(size_t)(b * SS + m) * NI + ((nck ^ (m & 15)) << 3) + npos] = f2bf(acc[mt][r]);
    }
  }
}

// ---------------- K2 stage-2: s_hd/s_hs/s_ds (192x192, K=256), MFMA ----------------
// grid (3, 4) = (which, b). 384 threads = 6 waves (1 n-strip each).
__global__ __launch_bounds__(384, 1) void k_s2(
    const uint16_t* __restrict__ HH, const uint16_t* __restrict__ HD,
    const uint16_t* __restrict__ dU16, const uint16_t* __restrict__ T216, const uint16_t* __restrict__ TZ16,
    float* __restrict__ s_hd, float* __restrict__ s_hs, float* __restrict__ s_ds) {
  __shared__ __align__(16) uint16_t Ah[192 * 128];   // 48 KB
  __shared__ __align__(16) uint16_t Bh[192 * 128];   // 48 KB
  const int which = blockIdx.x, b = blockIdx.y;
  const uint16_t* As = (which == 2) ? HD : HH;
  const uint16_t* Bs = (which == 0) ? dU16 : (which == 1) ? T216 : TZ16;
  float* Os = (which == 0) ? s_hd : (which == 1) ? s_hs : s_ds;
  const int tid = threadIdx.x, lane = tid & 63, w = tid >> 6;
  const int l31 = lane & 31, l5 = lane >> 5;
  f32x16 acc[6] = {};

  #pragma unroll
  for (int kh = 0; kh < 2; ++kh) {
    const int kbase = kh * 128;
    if (kh) __syncthreads();
    #pragma unroll
    for (int i = 0; i < 8; ++i) {
      const int slot = i * 384 + tid;
      const int row = slot >> 4, ck = slot & 15;
      const uint16_t* src = As + (size_t)(b * SS + row) * NI + kbase + ck * 8;
      __builtin_amdgcn_global_load_lds((const __attribute__((address_space(1))) void*)src,
          (__attribute__((address_space(3))) void*)(Ah + (size_t)slot * 8), 16, 0, 0);
    }
    #pragma unroll
    for (int i = 0; i < 8; ++i) {
      const int slot = i * 384 + tid;
      const int row = slot >> 4, ck = slot & 15;
      const uint16_t* src = Bs + (size_t)(b * SS + row) * NI + kbase + ck * 8;
      __builtin_amdgcn_global_load_lds((const __attribute__((address_space(1))) void*)src,
          (__attribute__((address_space(3))) void*)(Bh + (size_t)slot * 8), 16, 0, 0);
    }
    __syncthreads();
    const int brow = w * 32 + l31;
    const int bbyte = brow * 256;
    const int bmask = brow & 15;
    #pragma unroll
    for (int ks = 0; ks < 8; ++ks) {
      const int sl = ks * 2 + l5;
      bf16x8 bf = *reinterpret_cast<const bf16x8*>((const char*)Bh + bbyte + ((sl ^ bmask) << 4));
      #pragma unroll
      for (int mt = 0; mt < 6; ++mt) {
        const int ar = mt * 32 + l31;
        bf16x8 af = *reinterpret_cast<const bf16x8*>((const char*)Ah + ar * 256 + ((sl ^ (ar & 15)) << 4));
        acc[mt] = __builtin_amdgcn_mfma_f32_32x32x16_bf16(af, bf, acc[mt], 0, 0, 0);
      }
    }
  }
  const int n = w * 32 + l31;
  #pragma unroll
  for (int mt = 0; mt < 6; ++mt) {
    #pragma unroll
    for (int r = 0; r < 16; ++r) {
      const int m = mt * 32 + (r & 3) + 8 * (r >> 2) + 4 * l5;
      Os[(size_t)(b * SS + m) * SS + n] = acc[mt][r];
    }
  }
}

// ---------------- K3: main GEMM (R8-validated body, swizzled-storage addressing) ----------------
__global__ __launch_bounds__(384, 3) void k3_big(
    const uint16_t* __restrict__ HH, const uint16_t* __restrict__ HS,
    const float* __restrict__ h_dep, const float* __restrict__ partial,
    const float* __restrict__ s_hd, const float* __restrict__ s_hs,
    const float* __restrict__ s_ds,
    const float* __restrict__ bias, float* __restrict__ out) {
  __shared__ __align__(16) uint16_t Btile[SS * 128];   // 48 KB
  __shared__ __align__(16) uint16_t Atile[96 * 128];   // 24 KB
  __shared__ uint16_t cvec[NI];
  const int d = blockIdx.x, hb = blockIdx.y, b = blockIdx.z;
  const int tid = threadIdx.x;
  const int lane = tid & 63, w = tid >> 6;
  const int whb = (w >> 1) * 32;
  const int wsb = (w & 1) * 96;
  const int l31 = lane & 31, l5 = lane >> 5;

  if (tid < NI) {
    float wr = 0.f;
    #pragma unroll
    for (int q = 0; q < 8; ++q) wr += partial[8 * tid + q];
    cvec[tid] = f2bf(wr * h_dep[(b * SS + d) * NI + tid]);
  }
  __syncthreads();

  f32x16 acc0 = {}, acc1 = {}, acc2 = {};

  #pragma unroll
  for (int half = 0; half < 2; ++half) {
    const int kbase = half * 128;
    // B-tile: HS storage already swizzled -> linear copy
    #pragma unroll
    for (int i = 0; i < 8; ++i) {
      const int slot = (w * 8 + i) * 64 + lane;
      const int row = slot >> 4;
      const uint16_t* src = HS + ((size_t)(b * SS + row) << 8) + kbase + (slot & 15) * 8;
      __builtin_amdgcn_global_load_lds(
          (const __attribute__((address_space(1))) void*)src,
          (__attribute__((address_space(3))) void*)(Btile + (size_t)slot * 8),
          16, 0, 0);
    }
    // A-tile: HH (swizzled storage) * cvec (logical) -> LDS (linear write = swizzled layout)
    #pragma unroll
    for (int i = 0; i < 4; ++i) {
      const int c = i * 384 + tid;
      const int row = c >> 4;
      const int kc = c & 15;
      const int lcl = kc ^ (row & 15);
      const uint4 cv4 = *(const uint4*)(cvec + kbase + lcl * 8);
      const uint4 hh4 = *(const uint4*)(HH + ((size_t)(b * SS + hb * 96 + row) << 8) + kbase + kc * 8);
      uint4 a4;
      a4.x = bfmul2(hh4.x, cv4.x);
      a4.y = bfmul2(hh4.y, cv4.y);
      a4.z = bfmul2(hh4.z, cv4.z);
      a4.w = bfmul2(hh4.w, cv4.w);
      *(uint4*)((char*)Atile + row * 256 + (kc << 4)) = a4;
    }
    __syncthreads();
    const int arow = whb + l31;
    const int abyte = arow * 256;
    const int amask = (arow & 15);
    #pragma unroll
    for (int ks = 0; ks < 8; ++ks) {
      const int sl = ks * 2 + l5;
      bf16x8 af = *reinterpret_cast<const bf16x8*>((const char*)Atile + abyte + ((sl ^ amask) << 4));
      {
        const int brow = wsb + l31;
        bf16x8 bf = *reinterpret_cast<const bf16x8*>((const char*)Btile + brow * 256 + ((sl ^ (brow & 15)) << 4));
        acc0 = __builtin_amdgcn_mfma_f32_32x32x16_bf16(af, bf, acc0, 0, 0, 0);
      }
      {
        const int brow = wsb + 32 + l31;
        bf16x8 bf = *reinterpret_cast<const bf16x8*>((const char*)Btile + brow * 256 + ((sl ^ (brow & 15)) << 4));
        acc1 = __builtin_amdgcn_mfma_f32_32x32x16_bf16(af, bf, acc1, 0, 0, 0);
      }
      {
        const int brow = wsb + 64 + l31;
        bf16x8 bf = *reinterpret_cast<const bf16x8*>((const char*)Btile + brow * 256 + ((sl ^ (brow & 15)) << 4));
        acc2 = __builtin_amdgcn_mfma_f32_32x32x16_bf16(af, bf, acc2, 0, 0, 0);
      }
    }
    __syncthreads();
  }

  const float bias0 = bias[0];
  float chd[16];
  #pragma unroll
  for (int r = 0; r < 16; ++r) {
    const int h = hb * 96 + whb + (r & 3) + 8 * (r >> 2) + 4 * l5;
    chd[r] = s_hd[(b * SS + h) * SS + d] + bias0;
  }
  #pragma unroll
  for (int t = 0; t < 3; ++t) {
    const int s = wsb + t * 32 + l31;
    const float dsv = s_ds[(b * SS + d) * SS + s];
    const f32x16 a = (t == 0) ? acc0 : (t == 1) ? acc1 : acc2;
    #pragma unroll
    for (int r = 0; r < 16; ++r) {
      const int h = hb * 96 + whb + (r & 3) + 8 * (r >> 2) + 4 * l5;
      const float v = a[r] + chd[r] + s_hs[(b * SS + h) * SS + s] + dsv;
      out[((size_t)(b * SS + h) * SS + d) * SS + s] = v;
    }
  }
}

extern "C" void kernel_launch(void* const* d_in, const int* in_sizes, int n_in,
                              void* d_out, int out_size, void* d_ws, size_t ws_size,
                              hipStream_t stream) {
  const float* h_head = (const float*)d_in[0];
  const float* h_dep  = (const float*)d_in[1];
  const float* h_sib  = (const float*)d_in[2];
  const float* W_tri  = (const float*)d_in[3];
  const float* U_hd   = (const float*)d_in[4];
  const float* V_hs   = (const float*)d_in[5];
  const float* Z_ds   = (const float*)d_in[6];
  const float* bias   = (const float*)d_in[7];
  float* out = (float*)d_out;

  float* ws = (float*)d_ws;
  float* partial = ws;          ws += 2048;
  float* s_hd    = ws;          ws += NB * SS * SS;
  float* s_hs    = ws;          ws += NB * SS * SS;
  float* s_ds    = ws;          ws += NB * SS * SS;
  uint16_t* HH   = (uint16_t*)ws;
  uint16_t* HD   = HH + NB * SS * NI;
  uint16_t* HS   = HD + NB * SS * NI;
  uint16_t* U16  = HS + NB * SS * NI;
  uint16_t* V16  = U16 + NI * NI;
  uint16_t* Z16  = V16 + NI * NI;
  uint16_t* dU16 = Z16 + NI * NI;
  uint16_t* T216 = dU16 + NB * SS * NI;
  uint16_t* TZ16 = T216 + NB * SS * NI;

  k0<<<2176, 256, 0, stream>>>(W_tri, h_head, h_dep, h_sib, U_hd, V_hs, Z_ds,
                               partial, HH, HD, HS, U16, V16, Z16);
  k_s1<<<dim3(3, 2, NB), 256, 0, stream>>>(HD, HS, U16, V16, Z16, dU16, T216, TZ16);
  k_s2<<<dim3(3, NB), 384, 0, stream>>>(HH, HD, dU16, T216, TZ16, s_hd, s_hs, s_ds);
  k3_big<<<dim3(SS, 2, NB), 384, 0, stream>>>(HH, HS, h_dep, partial,
                                              s_hd, s_hs, s_ds, bias, out);
}